// Round 8
// baseline (434.708 us; speedup 1.0000x reference)
//
#include <hip/hip_runtime.h>
#include <hip/hip_bf16.h>

typedef __attribute__((ext_vector_type(8))) __bf16 bf16x8;
typedef __attribute__((ext_vector_type(4))) float f32x4;
typedef __attribute__((ext_vector_type(4))) unsigned short ushort4v;
typedef unsigned short u16;

// ---------- helpers ----------
__device__ __forceinline__ u16 f2bf_bits(float f) {
    union { float f; unsigned int u; } x; x.f = f;
    unsigned int r = x.u + 0x7FFFu + ((x.u >> 16) & 1u);   // RNE
    return (u16)(r >> 16);
}

__device__ __forceinline__ void gload_lds16(const void* g, void* l) {
    __builtin_amdgcn_global_load_lds(
        (const __attribute__((address_space(1))) void*)g,
        (__attribute__((address_space(3))) void*)l, 16, 0, 0);
}

#define BARRIER()  __builtin_amdgcn_s_barrier()
#define VMW0()     asm volatile("s_waitcnt vmcnt(0)" ::: "memory")

// ---------- f32 -> bf16 convert (contiguous) ----------
__global__ void cvt4(const float* __restrict__ in, u16* __restrict__ out, int n) {
    int i = (blockIdx.x * 256 + threadIdx.x) << 2;
    if (i >= n) return;
    f32x4 v = *reinterpret_cast<const f32x4*>(in + i);
    ushort4v o;
    o.x = f2bf_bits(v.x); o.y = f2bf_bits(v.y);
    o.z = f2bf_bits(v.z); o.w = f2bf_bits(v.w);
    *reinterpret_cast<ushort4v*>(out + i) = o;
}

// ---------- f32 (R x C) -> bf16 transposed (C x R), 64x64 tiles ----------
__global__ __launch_bounds__(256)
void transpose_cvt64(const float* __restrict__ in, u16* __restrict__ out,
                     int R, int C) {
    __shared__ float t[64][67];
    const int c0 = blockIdx.x << 6;
    const int r0 = blockIdx.y << 6;
    const int tx = threadIdx.x & 15;
    const int ty = threadIdx.x >> 4;
    #pragma unroll
    for (int j = 0; j < 4; ++j) {
        f32x4 v = *reinterpret_cast<const f32x4*>(
            &in[(size_t)(r0 + ty + 16 * j) * C + c0 + (tx << 2)]);
        *reinterpret_cast<f32x4*>(&t[ty + 16 * j][tx << 2]) = v;
    }
    __syncthreads();
    const int oc = threadIdx.x >> 2;
    const int rr = (threadIdx.x & 3) << 2;
    #pragma unroll
    for (int j = 0; j < 4; ++j) {
        const int r = rr + 16 * j;
        ushort4v o;
        o.x = f2bf_bits(t[r + 0][oc]);
        o.y = f2bf_bits(t[r + 1][oc]);
        o.z = f2bf_bits(t[r + 2][oc]);
        o.w = f2bf_bits(t[r + 3][oc]);
        *reinterpret_cast<ushort4v*>(&out[(size_t)(c0 + oc) * R + r0 + r]) = o;
    }
}

// ---------- reparameterization ----------
__global__ void sampler(const float* __restrict__ mu, const float* __restrict__ lv,
                        const float* __restrict__ eps, u16* __restrict__ zs, int n) {
    int i = blockIdx.x * 256 + threadIdx.x;
    if (i >= n) return;
    float v = mu[i] + __expf(0.5f * lv[i]) * eps[i];
    zs[i] = f2bf_bits(v);
}

// ---------- 128x128 2-phase GEMM (z-GEMM N=1024) ----------
template<int MODE>
__global__ __launch_bounds__(256)
void gemm_bt(const u16* __restrict__ A, const u16* __restrict__ Bt,
             const float* __restrict__ bias,
             u16* __restrict__ obf, float* __restrict__ of32, float* __restrict__ olv,
             int M, int N, int K)
{
    __shared__ u16 As[128 * 32];
    __shared__ u16 Bs[128 * 32];

    const int tid  = threadIdx.x;
    const int lane = tid & 63;
    const int w    = tid >> 6;
    const int wr   = w >> 1;
    const int wc   = w & 1;

    const int nbx  = N >> 7;
    const int brow = (blockIdx.x / nbx) << 7;
    const int bcol = (blockIdx.x % nbx) << 7;

    const int srow = (w << 4) + (lane >> 2);
    const int scol = (lane & 3) << 3;
    const size_t aoff0 = (size_t)(brow + srow) * K + scol;
    const size_t aoff1 = (size_t)(brow + 64 + srow) * K + scol;
    const size_t boff0 = (size_t)(bcol + srow) * K + scol;
    const size_t boff1 = (size_t)(bcol + 64 + srow) * K + scol;

    u16* asl0 = &As[(w << 9)];
    u16* asl1 = &As[2048 + (w << 9)];
    u16* bsl0 = &Bs[(w << 9)];
    u16* bsl1 = &Bs[2048 + (w << 9)];

    f32x4 acc[4][4];
    #pragma unroll
    for (int m = 0; m < 4; ++m)
        #pragma unroll
        for (int n = 0; n < 4; ++n)
            acc[m][n] = (f32x4)(0.0f);

    const int ar   = (wr << 6) + (lane & 15);
    const int br   = (wc << 6) + (lane & 15);
    const int koff = (lane >> 4) << 3;

    for (int kt = 0; kt < K; kt += 32) {
        __syncthreads();
        gload_lds16(A  + aoff0 + kt, asl0);
        gload_lds16(A  + aoff1 + kt, asl1);
        gload_lds16(Bt + boff0 + kt, bsl0);
        gload_lds16(Bt + boff1 + kt, bsl1);
        __syncthreads();

        bf16x8 av[4], bv[4];
        #pragma unroll
        for (int m = 0; m < 4; ++m)
            av[m] = *reinterpret_cast<const bf16x8*>(&As[(ar + (m << 4)) * 32 + koff]);
        #pragma unroll
        for (int n = 0; n < 4; ++n)
            bv[n] = *reinterpret_cast<const bf16x8*>(&Bs[(br + (n << 4)) * 32 + koff]);

        #pragma unroll
        for (int m = 0; m < 4; ++m)
            #pragma unroll
            for (int n = 0; n < 4; ++n)
                acc[m][n] = __builtin_amdgcn_mfma_f32_16x16x32_bf16(
                    av[m], bv[n], acc[m][n], 0, 0, 0);
    }

    float bv4[4];
    #pragma unroll
    for (int n = 0; n < 4; ++n)
        bv4[n] = bias[bcol + (wc << 6) + (n << 4) + (lane & 15)];

    const int erow0 = brow + (wr << 6) + ((lane >> 4) << 2);
    const int ecol0 = bcol + (wc << 6) + (lane & 15);

    #pragma unroll
    for (int m = 0; m < 4; ++m) {
        #pragma unroll
        for (int i = 0; i < 4; ++i) {
            const int r = erow0 + (m << 4) + i;
            #pragma unroll
            for (int n = 0; n < 4; ++n) {
                const int c = ecol0 + (n << 4);
                float v = acc[m][n][i] + bv4[n];
                if (MODE == 0) {
                    v = v > 0.0f ? v : 0.0f;
                    obf[(size_t)r * N + c] = f2bf_bits(v);
                } else if (MODE == 1) {
                    of32[(size_t)r * N + c] = v;
                } else {
                    if (c < 512) of32[(size_t)r * 512 + c] = v;
                    else         olv[(size_t)r * 512 + (c - 512)] = v;
                }
            }
        }
    }
}

// ---------- 256x256 mono-phase GEMM: 1 K-tile / phase, 2 barriers / tile ----------
// phase t (c=t&1, cn=c^1):
//   BAR1; STAGE(cn <- t+1); MM(g0xb0); MM(g0xb1); READ_A(c,g1); MM(g1xb0);
//   VMW0 (own stages, ~1900cy cover); BAR2 (all waves' stages visible);
//   READ_B0(cn); MM(g1xb1); READ_A(cn,g0); READ_B1(cn)   // consumed next phase
// Safety: end-reads crossing BAR1 always target buf c (consumed), never the
// staged buf cn; stage visibility = per-wave VMW0 -> BAR2 -> reads (proven
// pattern); in-phase reads drained by consuming MFMAs' auto-lgkmcnt.
template<int MODE>
__global__ __launch_bounds__(512, 2)
void gemm256(const u16* __restrict__ A, const u16* __restrict__ Bt,
             const float* __restrict__ bias,
             u16* __restrict__ obf, float* __restrict__ of32,
             int M, int N, int K)
{
    extern __shared__ char lds[];
    const int tid  = threadIdx.x;
    const int lane = tid & 63;
    const int w    = tid >> 6;
    const int wr   = w >> 2;
    const int wc   = w & 3;

    int bid = blockIdx.x;
    const int cpx = gridDim.x >> 3;
    bid = (bid & 7) * cpx + (bid >> 3);
    const int nbx  = N >> 8;
    const int brow = (bid / nbx) << 8;
    const int bcol = (bid % nbx) << 8;

    const int srow  = tid >> 3;
    const int scole = (((tid & 7) ^ (srow & 7)) << 4) >> 1;
    const size_t aoff = (size_t)(brow + srow) * K + scole;
    const size_t boff = (size_t)(bcol + srow) * K + scole;
    const size_t rowK64 = (size_t)64 * K;
    const int wave1024 = w << 10;

    const int lo16 = (lane >> 4) << 4;
    const int swzm = (lane & 7) << 4;
    const int low0 = lo16 ^ swzm;
    const int low1 = (64 | lo16) ^ swzm;
    const int rA   = (lane & 15) << 7;
    const int rB   = ((((wc & 1) << 6) | (lane & 15)) << 7);
    const int regA = wr << 14;
    const int regB = 32768 + ((wc >> 1) << 14);

    bf16x8 a[4][2];
    bf16x8 b0[2][2];
    bf16x8 b1[2][2];
    f32x4 acc[8][4];
    #pragma unroll
    for (int m = 0; m < 8; ++m)
        #pragma unroll
        for (int n = 0; n < 4; ++n)
            acc[m][n] = (f32x4)(0.0f);

#define STAGE_A(buf, h, kt) do { \
    const u16* _s = A + aoff + (size_t)(h) * 128 * K + (size_t)(kt) * 64; \
    gload_lds16(_s,          lds + ((buf) << 16) + ((h) << 14) + wave1024); \
    gload_lds16(_s + rowK64, lds + ((buf) << 16) + ((h) << 14) + 8192 + wave1024); \
} while (0)

#define STAGE_B(buf, h, kt) do { \
    const u16* _s = Bt + boff + (size_t)(h) * 128 * K + (size_t)(kt) * 64; \
    gload_lds16(_s,          lds + ((buf) << 16) + 32768 + ((h) << 14) + wave1024); \
    gload_lds16(_s + rowK64, lds + ((buf) << 16) + 32768 + ((h) << 14) + 8192 + wave1024); \
} while (0)

#define READ_A(buf, g) do { \
    _Pragma("unroll") \
    for (int m = 0; m < 4; ++m) { \
        const int _b = ((buf) << 16) + regA + rA + ((((g) << 2) + m) << 11); \
        a[m][0] = *reinterpret_cast<const bf16x8*>(lds + _b + low0); \
        a[m][1] = *reinterpret_cast<const bf16x8*>(lds + _b + low1); \
    } \
} while (0)

#define READ_B0(buf) do { \
    _Pragma("unroll") \
    for (int n = 0; n < 2; ++n) { \
        const int _b = ((buf) << 16) + regB + rB + (n << 11); \
        b0[n][0] = *reinterpret_cast<const bf16x8*>(lds + _b + low0); \
        b0[n][1] = *reinterpret_cast<const bf16x8*>(lds + _b + low1); \
    } \
} while (0)

#define READ_B1(buf) do { \
    _Pragma("unroll") \
    for (int n = 0; n < 2; ++n) { \
        const int _b = ((buf) << 16) + regB + rB + ((n + 2) << 11); \
        b1[n][0] = *reinterpret_cast<const bf16x8*>(lds + _b + low0); \
        b1[n][1] = *reinterpret_cast<const bf16x8*>(lds + _b + low1); \
    } \
} while (0)

#define MM(bx, mb, nb) do { \
    __builtin_amdgcn_s_setprio(1); \
    _Pragma("unroll") \
    for (int m = 0; m < 4; ++m) \
        _Pragma("unroll") \
        for (int n = 0; n < 2; ++n) \
            _Pragma("unroll") \
            for (int s = 0; s < 2; ++s) \
                acc[(mb) + m][(nb) + n] = __builtin_amdgcn_mfma_f32_16x16x32_bf16( \
                    a[m][s], bx[n][s], acc[(mb) + m][(nb) + n], 0, 0, 0); \
    __builtin_amdgcn_s_setprio(0); \
} while (0)

    const int NT = K >> 6;   // K-tiles of 64

    // ---- prologue: tile0 -> buf0; sync; read tile0 frags ----
    STAGE_A(0, 0, 0); STAGE_A(0, 1, 0); STAGE_B(0, 0, 0); STAGE_B(0, 1, 0);
    VMW0(); BARRIER();
    READ_A(0, 0); READ_B0(0); READ_B1(0);

    for (int t = 0; t < NT; ++t) {
        const int c  = t & 1;
        const int cn = c ^ 1;
        const int tn = (t + 1 < NT) ? t + 1 : NT - 1;  // dead-stage clamp on last tile

        BARRIER();                                      // BAR1
        STAGE_A(cn, 0, tn); STAGE_A(cn, 1, tn);
        STAGE_B(cn, 0, tn); STAGE_B(cn, 1, tn);

        MM(b0, 0, 0);                                   // g0 x n0-1
        MM(b1, 0, 2);                                   // g0 x n2-3
        READ_A(c, 1);                                   // g1 frags (covered by MFMA drain)
        MM(b0, 4, 0);                                   // g1 x n0-1

        VMW0();                                         // own stages done (~1900cy cover)
        BARRIER();                                      // BAR2: all waves' stages visible

        READ_B0(cn);                                    // next-tile b0 (early)
        MM(b1, 4, 2);                                   // g1 x n2-3
        READ_A(cn, 0); READ_B1(cn);                     // next-tile a-g0, b1
    }

    // ---- epilogue ----
    float bb[4];
    #pragma unroll
    for (int n = 0; n < 4; ++n)
        bb[n] = bias[bcol + (wc << 6) + (n << 4) + (lane & 15)];

    const int erow0 = brow + (wr << 7) + ((lane >> 4) << 2);
    const int ecol0 = bcol + (wc << 6) + (lane & 15);

    #pragma unroll
    for (int m = 0; m < 8; ++m) {
        #pragma unroll
        for (int i = 0; i < 4; ++i) {
            const int r = erow0 + (m << 4) + i;
            #pragma unroll
            for (int n = 0; n < 4; ++n) {
                const int c = ecol0 + (n << 4);
                float v = acc[m][n][i] + bb[n];
                if (MODE == 0) {
                    v = v > 0.0f ? v : 0.0f;
                    obf[(size_t)r * N + c] = f2bf_bits(v);
                } else {
                    of32[(size_t)r * N + c] = v;
                }
            }
        }
    }
#undef STAGE_A
#undef STAGE_B
#undef READ_A
#undef READ_B0
#undef READ_B1
#undef MM
}

// ---------- launch ----------
extern "C" void kernel_launch(void* const* d_in, const int* in_sizes, int n_in,
                              void* d_out, int out_size, void* d_ws, size_t ws_size,
                              hipStream_t stream) {
    const float* x   = (const float*)d_in[0];
    const float* We1 = (const float*)d_in[1];
    const float* be1 = (const float*)d_in[2];
    const float* We2 = (const float*)d_in[3];
    const float* be2 = (const float*)d_in[4];
    const float* Wd1 = (const float*)d_in[5];
    const float* bd1 = (const float*)d_in[6];
    const float* Wd2 = (const float*)d_in[7];
    const float* bd2 = (const float*)d_in[8];
    const float* eps = (const float*)d_in[9];

    const int B = 4096, D = 4096, H = 4096, LAT = 512;

    char* ws = (char*)d_ws;
    u16* xb  = (u16*)(ws);
    u16* w1t = (u16*)(ws + 33554432);
    u16* w2t = (u16*)(ws + 67108864);
    u16* w3t = (u16*)(ws + 75497472);
    u16* w4t = (u16*)(ws + 79691776);
    u16* h   = (u16*)(ws + 113246208);
    u16* zs  = w1t;
    u16* hd  = xb;

    float* recon = (float*)d_out;
    float* mu    = recon + (size_t)B * D;
    float* lv    = mu + (size_t)B * LAT;

    hipFuncSetAttribute(reinterpret_cast<const void*>(gemm256<0>),
                        hipFuncAttributeMaxDynamicSharedMemorySize, 131072);
    hipFuncSetAttribute(reinterpret_cast<const void*>(gemm256<1>),
                        hipFuncAttributeMaxDynamicSharedMemorySize, 131072);

    cvt4<<<(B * D / 4 + 255) / 256, 256, 0, stream>>>(x, xb, B * D);
    transpose_cvt64<<<dim3(H / 64, D / 64), 256, 0, stream>>>(We1, w1t, D, H);
    transpose_cvt64<<<dim3(2 * LAT / 64, H / 64), 256, 0, stream>>>(We2, w2t, H, 2 * LAT);
    transpose_cvt64<<<dim3(H / 64, LAT / 64), 256, 0, stream>>>(Wd1, w3t, LAT, H);
    transpose_cvt64<<<dim3(D / 64, H / 64), 256, 0, stream>>>(Wd2, w4t, H, D);

    // h = relu(x @ We1 + be1)        M=B, N=H, K=D
    gemm256<0><<<(B / 256) * (H / 256), 512, 131072, stream>>>(xb, w1t, be1, h, nullptr, B, H, D);
    // z = h @ We2 + be2 -> mu, logvar  (128^2, N=1024)
    gemm_bt<2><<<(B / 128) * (2 * LAT / 128), 256, 0, stream>>>(h, w2t, be2, nullptr, mu, lv, B, 2 * LAT, H);
    // zs = mu + exp(0.5*lv)*eps
    sampler<<<(B * LAT + 255) / 256, 256, 0, stream>>>(mu, lv, eps, zs, B * LAT);
    // hd = relu(zs @ Wd1 + bd1)      M=B, N=H, K=LAT
    gemm256<0><<<(B / 256) * (H / 256), 512, 131072, stream>>>(zs, w3t, bd1, hd, nullptr, B, H, LAT);
    // recon = hd @ Wd2 + bd2         M=B, N=D, K=H
    gemm256<1><<<(B / 256) * (D / 256), 512, 131072, stream>>>(hd, w4t, bd2, nullptr, recon, B, D, H);
}

// Round 9
// 371.947 us; speedup vs baseline: 1.1687x; 1.1687x over previous
//
#include <hip/hip_runtime.h>
#include <hip/hip_bf16.h>

typedef __attribute__((ext_vector_type(8))) __bf16 bf16x8;
typedef __attribute__((ext_vector_type(4))) float f32x4;
typedef __attribute__((ext_vector_type(4))) unsigned short ushort4v;
typedef unsigned short u16;

// ---------- helpers ----------
__device__ __forceinline__ u16 f2bf_bits(float f) {
    union { float f; unsigned int u; } x; x.f = f;
    unsigned int r = x.u + 0x7FFFu + ((x.u >> 16) & 1u);   // RNE
    return (u16)(r >> 16);
}

__device__ __forceinline__ void gload_lds16(const void* g, void* l) {
    __builtin_amdgcn_global_load_lds(
        (const __attribute__((address_space(1))) void*)g,
        (__attribute__((address_space(3))) void*)l, 16, 0, 0);
}

#define BARRIER()  __builtin_amdgcn_s_barrier()
#define LGKM0()    asm volatile("s_waitcnt lgkmcnt(0)" ::: "memory")
#define VMW8()     asm volatile("s_waitcnt vmcnt(8)" ::: "memory")

// ---------- f32 -> bf16 convert (contiguous) ----------
__global__ void cvt4(const float* __restrict__ in, u16* __restrict__ out, int n) {
    int i = (blockIdx.x * 256 + threadIdx.x) << 2;
    if (i >= n) return;
    f32x4 v = *reinterpret_cast<const f32x4*>(in + i);
    ushort4v o;
    o.x = f2bf_bits(v.x); o.y = f2bf_bits(v.y);
    o.z = f2bf_bits(v.z); o.w = f2bf_bits(v.w);
    *reinterpret_cast<ushort4v*>(out + i) = o;
}

// ---------- f32 (R x C) -> bf16 transposed (C x R), 64x64 tiles ----------
__global__ __launch_bounds__(256)
void transpose_cvt64(const float* __restrict__ in, u16* __restrict__ out,
                     int R, int C) {
    __shared__ float t[64][67];
    const int c0 = blockIdx.x << 6;
    const int r0 = blockIdx.y << 6;
    const int tx = threadIdx.x & 15;
    const int ty = threadIdx.x >> 4;
    #pragma unroll
    for (int j = 0; j < 4; ++j) {
        f32x4 v = *reinterpret_cast<const f32x4*>(
            &in[(size_t)(r0 + ty + 16 * j) * C + c0 + (tx << 2)]);
        *reinterpret_cast<f32x4*>(&t[ty + 16 * j][tx << 2]) = v;
    }
    __syncthreads();
    const int oc = threadIdx.x >> 2;
    const int rr = (threadIdx.x & 3) << 2;
    #pragma unroll
    for (int j = 0; j < 4; ++j) {
        const int r = rr + 16 * j;
        ushort4v o;
        o.x = f2bf_bits(t[r + 0][oc]);
        o.y = f2bf_bits(t[r + 1][oc]);
        o.z = f2bf_bits(t[r + 2][oc]);
        o.w = f2bf_bits(t[r + 3][oc]);
        *reinterpret_cast<ushort4v*>(&out[(size_t)(c0 + oc) * R + r0 + r]) = o;
    }
}

// ---------- split-K reduce + bias + reparameterization (fused) ----------
// P: 4 partials of (4096 x 1024) f32.  mu/lv: (4096 x 512) f32.  zs bf16.
__global__ __launch_bounds__(256)
void zred(const float* __restrict__ P, const float* __restrict__ be2,
          const float* __restrict__ eps, float* __restrict__ mu,
          float* __restrict__ lv, u16* __restrict__ zs) {
    const int i = blockIdx.x * 256 + threadIdx.x;      // over 4096*512/4
    const int r = i >> 7;
    const int c4 = (i & 127) << 2;
    const size_t base = (size_t)r * 1024 + c4;
    const size_t PS = (size_t)4096 * 1024;

    f32x4 m = *reinterpret_cast<const f32x4*>(P + base);
    f32x4 l = *reinterpret_cast<const f32x4*>(P + base + 512);
    #pragma unroll
    for (int s = 1; s < 4; ++s) {
        m += *reinterpret_cast<const f32x4*>(P + s * PS + base);
        l += *reinterpret_cast<const f32x4*>(P + s * PS + base + 512);
    }
    m += *reinterpret_cast<const f32x4*>(be2 + c4);
    l += *reinterpret_cast<const f32x4*>(be2 + 512 + c4);

    const size_t ob = (size_t)r * 512 + c4;
    *reinterpret_cast<f32x4*>(mu + ob) = m;
    *reinterpret_cast<f32x4*>(lv + ob) = l;

    f32x4 e = *reinterpret_cast<const f32x4*>(eps + ob);
    ushort4v o;
    o.x = f2bf_bits(m.x + __expf(0.5f * l.x) * e.x);
    o.y = f2bf_bits(m.y + __expf(0.5f * l.y) * e.y);
    o.z = f2bf_bits(m.z + __expf(0.5f * l.z) * e.z);
    o.w = f2bf_bits(m.w + __expf(0.5f * l.w) * e.w);
    *reinterpret_cast<ushort4v*>(zs + ob) = o;
}

// ---------- 256x256 8-phase GEMM, single-barrier phases (round-7 proven) ----------
// MODE 0: relu->bf16 obf. MODE 1: f32 of32. MODE 3: split-K f32 partial, no bias
//   (grid = tiles*4; sid = bid&3 selects K-slab of `ntiles` tiles at kbase=sid*ntiles,
//    output partial s at of32 + sid*M*N).
template<int MODE>
__global__ __launch_bounds__(512, 2)
void gemm256(const u16* __restrict__ A, const u16* __restrict__ Bt,
             const float* __restrict__ bias,
             u16* __restrict__ obf, float* __restrict__ of32,
             int M, int N, int K, int ntiles)
{
    extern __shared__ char lds[];
    const int tid  = threadIdx.x;
    const int lane = tid & 63;
    const int w    = tid >> 6;
    const int wr   = w >> 2;
    const int wc   = w & 3;

    int bid = blockIdx.x;
    int sid = 0;
    int nwg = gridDim.x;
    if (MODE == 3) { sid = bid & 3; bid >>= 2; nwg >>= 2; }
    const int cpx = nwg >> 3;
    bid = (bid & 7) * cpx + (bid >> 3);
    const int nbx  = N >> 8;
    const int brow = (bid / nbx) << 8;
    const int bcol = (bid % nbx) << 8;
    const int kbase = (MODE == 3) ? sid * ntiles : 0;
    float* pout = (MODE == 3) ? of32 + (size_t)sid * M * N : of32;

    const int srow  = tid >> 3;
    const int scole = (((tid & 7) ^ (srow & 7)) << 4) >> 1;
    const size_t aoff = (size_t)(brow + srow) * K + scole;
    const size_t boff = (size_t)(bcol + srow) * K + scole;
    const size_t rowK64 = (size_t)64 * K;
    const int wave1024 = w << 10;

    const int lo16 = (lane >> 4) << 4;
    const int swzm = (lane & 7) << 4;
    const int low0 = lo16 ^ swzm;
    const int low1 = (64 | lo16) ^ swzm;
    const int rA   = (lane & 15) << 7;
    const int rB   = ((((wc & 1) << 6) | (lane & 15)) << 7);
    const int regA = wr << 14;
    const int regB = 32768 + ((wc >> 1) << 14);

    bf16x8 a[4][2];
    bf16x8 b0[2][2];
    bf16x8 b1[2][2];
    f32x4 acc[8][4];
    #pragma unroll
    for (int m = 0; m < 8; ++m)
        #pragma unroll
        for (int n = 0; n < 4; ++n)
            acc[m][n] = (f32x4)(0.0f);

#define STAGE_A(buf, h, kt) do { \
    const u16* _s = A + aoff + (size_t)(h) * 128 * K + (size_t)(kt) * 64; \
    gload_lds16(_s,          lds + ((buf) << 16) + ((h) << 14) + wave1024); \
    gload_lds16(_s + rowK64, lds + ((buf) << 16) + ((h) << 14) + 8192 + wave1024); \
} while (0)

#define STAGE_B(buf, h, kt) do { \
    const u16* _s = Bt + boff + (size_t)(h) * 128 * K + (size_t)(kt) * 64; \
    gload_lds16(_s,          lds + ((buf) << 16) + 32768 + ((h) << 14) + wave1024); \
    gload_lds16(_s + rowK64, lds + ((buf) << 16) + 32768 + ((h) << 14) + 8192 + wave1024); \
} while (0)

#define READ_A(buf, g) do { \
    _Pragma("unroll") \
    for (int m = 0; m < 4; ++m) { \
        const int _b = ((buf) << 16) + regA + rA + ((((g) << 2) + m) << 11); \
        a[m][0] = *reinterpret_cast<const bf16x8*>(lds + _b + low0); \
        a[m][1] = *reinterpret_cast<const bf16x8*>(lds + _b + low1); \
    } \
} while (0)

#define READ_B0(buf) do { \
    _Pragma("unroll") \
    for (int n = 0; n < 2; ++n) { \
        const int _b = ((buf) << 16) + regB + rB + (n << 11); \
        b0[n][0] = *reinterpret_cast<const bf16x8*>(lds + _b + low0); \
        b0[n][1] = *reinterpret_cast<const bf16x8*>(lds + _b + low1); \
    } \
} while (0)

#define READ_B1(buf) do { \
    _Pragma("unroll") \
    for (int n = 0; n < 2; ++n) { \
        const int _b = ((buf) << 16) + regB + rB + ((n + 2) << 11); \
        b1[n][0] = *reinterpret_cast<const bf16x8*>(lds + _b + low0); \
        b1[n][1] = *reinterpret_cast<const bf16x8*>(lds + _b + low1); \
    } \
} while (0)

#define MM(bx, mb, nb) do { \
    __builtin_amdgcn_s_setprio(1); \
    _Pragma("unroll") \
    for (int m = 0; m < 4; ++m) \
        _Pragma("unroll") \
        for (int n = 0; n < 2; ++n) \
            _Pragma("unroll") \
            for (int s = 0; s < 2; ++s) \
                acc[(mb) + m][(nb) + n] = __builtin_amdgcn_mfma_f32_16x16x32_bf16( \
                    a[m][s], bx[n][s], acc[(mb) + m][(nb) + n], 0, 0, 0); \
    __builtin_amdgcn_s_setprio(0); \
} while (0)

    const int NIT = ntiles >> 1;   // 2 K-tiles of 64 per iteration

    // ---- prologue: tile kbase -> buf0, kbase+1 -> buf1 ----
    STAGE_A(0, 0, kbase); STAGE_A(0, 1, kbase); STAGE_B(0, 0, kbase); STAGE_B(0, 1, kbase);
    STAGE_A(1, 0, kbase + 1); STAGE_A(1, 1, kbase + 1); STAGE_B(1, 0, kbase + 1); STAGE_B(1, 1, kbase + 1);
    VMW8(); BARRIER();
    READ_A(0, 0); READ_B0(0);          // ph1 operands

    for (int it = 0; it < NIT; ++it) {
        const int tn0r = 2 * it + 2;
        const int tn1r = 2 * it + 3;
        const int tn0 = kbase + (tn0r < ntiles ? tn0r : ntiles - 1);  // dead-stage clamp
        const int tn1 = kbase + (tn1r < ntiles ? tn1r : ntiles - 1);

        // ph1
        BARRIER(); LGKM0();
        MM(b0, 0, 0);
        READ_B1(0);

        // ph2
        BARRIER(); LGKM0();
        STAGE_B(0, 0, tn0);            // B0 last read-issue: prev ph8
        MM(b1, 0, 2);
        READ_A(0, 1);

        // ph3
        BARRIER(); LGKM0();
        STAGE_B(0, 1, tn0);            // B1 last read-issue: ph1
        MM(b1, 4, 2);

        // ph4
        BARRIER(); LGKM0();
        STAGE_A(0, 0, tn0); STAGE_A(0, 1, tn0);  // A last read-issue: ph2
        MM(b0, 4, 0);
        VMW8();                        // drains prev-iter buf1 stages (lead 4 phases)
        READ_A(1, 0); READ_B0(1);

        // ph5
        BARRIER(); LGKM0();
        MM(b0, 0, 0);
        READ_B1(1);

        // ph6
        BARRIER(); LGKM0();
        STAGE_B(1, 0, tn1);
        MM(b1, 0, 2);
        READ_A(1, 1);

        // ph7
        BARRIER(); LGKM0();
        STAGE_B(1, 1, tn1);
        MM(b1, 4, 2);

        // ph8
        BARRIER(); LGKM0();
        STAGE_A(1, 0, tn1); STAGE_A(1, 1, tn1);
        MM(b0, 4, 0);
        VMW8();                        // drains this-iter buf0 stages (lead 4 phases)
        READ_A(0, 0); READ_B0(0);
    }

    // ---- epilogue ----
    float bb[4];
    #pragma unroll
    for (int n = 0; n < 4; ++n)
        bb[n] = (MODE == 3) ? 0.0f : bias[bcol + (wc << 6) + (n << 4) + (lane & 15)];

    const int erow0 = brow + (wr << 7) + ((lane >> 4) << 2);
    const int ecol0 = bcol + (wc << 6) + (lane & 15);

    #pragma unroll
    for (int m = 0; m < 8; ++m) {
        #pragma unroll
        for (int i = 0; i < 4; ++i) {
            const int r = erow0 + (m << 4) + i;
            #pragma unroll
            for (int n = 0; n < 4; ++n) {
                const int c = ecol0 + (n << 4);
                float v = acc[m][n][i] + bb[n];
                if (MODE == 0) {
                    v = v > 0.0f ? v : 0.0f;
                    obf[(size_t)r * N + c] = f2bf_bits(v);
                } else {
                    pout[(size_t)r * N + c] = v;
                }
            }
        }
    }
#undef STAGE_A
#undef STAGE_B
#undef READ_A
#undef READ_B0
#undef READ_B1
#undef MM
}

// ---------- launch ----------
extern "C" void kernel_launch(void* const* d_in, const int* in_sizes, int n_in,
                              void* d_out, int out_size, void* d_ws, size_t ws_size,
                              hipStream_t stream) {
    const float* x   = (const float*)d_in[0];
    const float* We1 = (const float*)d_in[1];
    const float* be1 = (const float*)d_in[2];
    const float* We2 = (const float*)d_in[3];
    const float* be2 = (const float*)d_in[4];
    const float* Wd1 = (const float*)d_in[5];
    const float* bd1 = (const float*)d_in[6];
    const float* Wd2 = (const float*)d_in[7];
    const float* bd2 = (const float*)d_in[8];
    const float* eps = (const float*)d_in[9];

    const int B = 4096, D = 4096, H = 4096, LAT = 512;

    // workspace layout (lifetimes traced):
    //   [0, 33.5M)      xb (x bf16; dead after G1) -> then partials p0,p1 -> then hd
    //   [33.5M, 67.1M)  w1t (dead after G1)        -> then partials p2,p3
    //   [67.1M, 75.5M)  w2t (dead after z-GEMM)
    //   [75.5M, 79.7M)  w3t (needed by G3)
    //   [79.7M, 113.2M) w4t (needed by G5)
    //   [113.2M,146.8M) h (dead after z-GEMM) -> zs at its start (4.2M)
    char* ws = (char*)d_ws;
    u16*   xb   = (u16*)(ws);
    u16*   w1t  = (u16*)(ws + 33554432);
    u16*   w2t  = (u16*)(ws + 67108864);
    u16*   w3t  = (u16*)(ws + 75497472);
    u16*   w4t  = (u16*)(ws + 79691776);
    u16*   h    = (u16*)(ws + 113246208);
    float* part = (float*)(ws);                 // 4 x (4096x1024) f32 = 67.1 MB
    u16*   zs   = (u16*)(ws + 113246208);       // over dead h
    u16*   hd   = (u16*)(ws);                   // over dead partials

    float* recon = (float*)d_out;
    float* mu    = recon + (size_t)B * D;
    float* lv    = mu + (size_t)B * LAT;

    hipFuncSetAttribute(reinterpret_cast<const void*>(gemm256<0>),
                        hipFuncAttributeMaxDynamicSharedMemorySize, 131072);
    hipFuncSetAttribute(reinterpret_cast<const void*>(gemm256<1>),
                        hipFuncAttributeMaxDynamicSharedMemorySize, 131072);
    hipFuncSetAttribute(reinterpret_cast<const void*>(gemm256<3>),
                        hipFuncAttributeMaxDynamicSharedMemorySize, 131072);

    cvt4<<<(B * D / 4 + 255) / 256, 256, 0, stream>>>(x, xb, B * D);
    transpose_cvt64<<<dim3(H / 64, D / 64), 256, 0, stream>>>(We1, w1t, D, H);
    transpose_cvt64<<<dim3(2 * LAT / 64, H / 64), 256, 0, stream>>>(We2, w2t, H, 2 * LAT);
    transpose_cvt64<<<dim3(H / 64, LAT / 64), 256, 0, stream>>>(Wd1, w3t, LAT, H);
    transpose_cvt64<<<dim3(D / 64, H / 64), 256, 0, stream>>>(Wd2, w4t, H, D);

    // G1: h = relu(x @ We1 + be1)    M=B, N=H, K=D, 64 tiles
    gemm256<0><<<(B / 256) * (H / 256), 512, 131072, stream>>>(
        xb, w1t, be1, h, nullptr, B, H, D, D / 64);
    // z-GEMM split-K=4: partials = h @ We2 (k-slab per sid), 16 tiles each
    gemm256<3><<<(B / 256) * (2 * LAT / 256) * 4, 512, 131072, stream>>>(
        h, w2t, nullptr, nullptr, part, B, 2 * LAT, H, (H / 64) / 4);
    // reduce + bias + sampler: mu, lv, zs
    zred<<<(B * LAT / 4) / 256, 256, 0, stream>>>(part, be2, eps, mu, lv, zs);
    // G3: hd = relu(zs @ Wd1 + bd1)  M=B, N=H, K=LAT, 8 tiles
    gemm256<0><<<(B / 256) * (H / 256), 512, 131072, stream>>>(
        zs, w3t, bd1, hd, nullptr, B, H, LAT, LAT / 64);
    // G5: recon = hd @ Wd2 + bd2     M=B, N=D, K=H, 64 tiles
    gemm256<1><<<(B / 256) * (D / 256), 512, 131072, stream>>>(
        hd, w4t, bd2, nullptr, recon, B, D, H, H / 64);
}